// Round 1
// baseline (23834.166 us; speedup 1.0000x reference)
//
#include <hip/hip_runtime.h>
#include <math.h>

#define TT 64
#define BB 256
#define OBS 512
#define ACTN 16
#define EMB 512
#define HID 1024
#define NCAT 32
#define NCLS 32
#define ZD 1024
#define G3 3072

// ---------------------------------------------------------------- one-hot -> index
__global__ void k_idx(const float* __restrict__ obs, const float* __restrict__ act,
                      int* __restrict__ obs_idx, int* __restrict__ act_idx) {
    int wave = (blockIdx.x * blockDim.x + threadIdx.x) >> 6;
    int lane = threadIdx.x & 63;
    if (wave >= TT * BB) return;
    const float* o = obs + (size_t)wave * OBS;
    int found = -1;
    #pragma unroll
    for (int j = 0; j < 8; ++j) {
        float v = o[lane + 64 * j];
        if (v > 0.5f) found = lane + 64 * j;
    }
    unsigned long long m = __ballot(found >= 0);
    int src = __ffsll(m) - 1;
    int oidx = __shfl(found, src);
    int af = -1;
    if (lane < ACTN) {
        float v = act[(size_t)wave * ACTN + lane];
        if (v > 0.5f) af = lane;
    }
    unsigned long long m2 = __ballot(af >= 0);
    int src2 = __ffsll(m2) - 1;
    int aidx = __shfl(af, src2);
    if (lane == 0) { obs_idx[wave] = oidx; act_idx[wave] = aidx; }
}

// ---------------------------------------------------------------- embed precompute
// embed[t,b,:] = elu(We1[obs_idx] + be1) @ We2 + be2 ; 8 rows per block
__global__ void k_embed(const int* __restrict__ obs_idx,
                        const float* __restrict__ We1, const float* __restrict__ be1,
                        const float* __restrict__ We2, const float* __restrict__ be2,
                        float* __restrict__ embed) {
    __shared__ float e1[8][64];
    int r0 = blockIdx.x * 8;
    int tid = threadIdx.x;
    for (int l = tid; l < 8 * 64; l += 256) {
        int r = l >> 6, k = l & 63;
        int oi = obs_idx[r0 + r];
        float v = We1[oi * 64 + k] + be1[k];
        e1[r][k] = v > 0.f ? v : (expf(v) - 1.f);
    }
    __syncthreads();
    for (int r = 0; r < 8; ++r) {
        for (int n = tid; n < EMB; n += 256) {
            float acc = be2[n];
            #pragma unroll 8
            for (int k = 0; k < 64; ++k) acc += e1[r][k] * We2[k * EMB + n];
            embed[(size_t)(r0 + r) * EMB + n] = acc;
        }
    }
}

// ---------------------------------------------------------------- generic fp32 GEMM
// C[256,N] = act(concat(A1[256,K1], A2[256,K2]) @ W[K,N] + bias), 64x64 tile, 4x4 micro
struct GemmJob {
    const float* A1; int K1;
    const float* A2; int K2;
    const float* W; const float* bias;
    float* C; int N; int act;   // 0 none, 1 elu
};

__global__ __launch_bounds__(256) void k_gemm(GemmJob j0, GemmJob j1) {
    GemmJob j = (blockIdx.z == 0) ? j0 : j1;
    if ((int)blockIdx.x >= (j.N >> 6)) return;
    __shared__ float As[16][68];
    __shared__ float Ws[16][64];
    int tid = threadIdx.x;
    int m0 = blockIdx.y * 64;
    int n0 = blockIdx.x * 64;
    int K = j.K1 + j.K2;
    int tx = tid & 15, ty = tid >> 4;
    float acc[4][4] = {{0.f}};
    int la = tid * 4;
    int am = la >> 4;          // 0..63
    int ak = la & 15;          // 0,4,8,12
    int wn = tid & 63;
    int wk = tid >> 6;         // 0..3
    for (int kt = 0; kt < K; kt += 16) {
        int kg = kt + ak;
        float4 av;
        if (kg < j.K1) av = *(const float4*)(j.A1 + (size_t)(m0 + am) * j.K1 + kg);
        else           av = *(const float4*)(j.A2 + (size_t)(m0 + am) * j.K2 + (kg - j.K1));
        As[ak + 0][am] = av.x; As[ak + 1][am] = av.y;
        As[ak + 2][am] = av.z; As[ak + 3][am] = av.w;
        #pragma unroll
        for (int i = 0; i < 4; ++i)
            Ws[wk + 4 * i][wn] = j.W[(size_t)(kt + wk + 4 * i) * j.N + n0 + wn];
        __syncthreads();
        #pragma unroll
        for (int kk = 0; kk < 16; ++kk) {
            float a[4], b[4];
            #pragma unroll
            for (int r = 0; r < 4; ++r) a[r] = As[kk][ty * 4 + r];
            #pragma unroll
            for (int c = 0; c < 4; ++c) b[c] = Ws[kk][tx * 4 + c];
            #pragma unroll
            for (int r = 0; r < 4; ++r)
                #pragma unroll
                for (int c = 0; c < 4; ++c) acc[r][c] += a[r] * b[c];
        }
        __syncthreads();
    }
    #pragma unroll
    for (int r = 0; r < 4; ++r) {
        int row = m0 + ty * 4 + r;
        #pragma unroll
        for (int c = 0; c < 4; ++c) {
            int col = n0 + tx * 4 + c;
            float v = acc[r][c] + j.bias[col];
            if (j.act == 1) v = v > 0.f ? v : (expf(v) - 1.f);
            j.C[(size_t)row * j.N + col] = v;
        }
    }
}

// ---------------------------------------------------------------- GRU elementwise update
// gi via one-hot z gather (32 rows of Wi) + action row + bi; h updated in place
__global__ void k_gru_up(const float* __restrict__ gh, const float* __restrict__ Wi,
                         const float* __restrict__ bi, const int* __restrict__ act_idx_t,
                         const int* __restrict__ zidx, float* __restrict__ h, int t) {
    __shared__ int zs[32];
    __shared__ int arow;
    int b = blockIdx.x;
    int tid = threadIdx.x;
    if (tid < 32 && t > 0) zs[tid] = zidx[b * 32 + tid];
    if (tid == 0) arow = ZD + act_idx_t[b];
    __syncthreads();
    for (int it = 0; it < 4; ++it) {
        int jc = it * 256 + tid;
        float gr = bi[jc]        + Wi[(size_t)arow * G3 + jc];
        float gu = bi[1024 + jc] + Wi[(size_t)arow * G3 + 1024 + jc];
        float gn = bi[2048 + jc] + Wi[(size_t)arow * G3 + 2048 + jc];
        if (t > 0) {
            #pragma unroll 4
            for (int c = 0; c < 32; ++c) {
                size_t ro = (size_t)(c * 32 + zs[c]) * G3;
                gr += Wi[ro + jc];
                gu += Wi[ro + 1024 + jc];
                gn += Wi[ro + 2048 + jc];
            }
        }
        float hr = gh[(size_t)b * G3 + jc];
        float hu = gh[(size_t)b * G3 + 1024 + jc];
        float hn = gh[(size_t)b * G3 + 2048 + jc];
        float r = 1.f / (1.f + expf(-(gr + hr)));
        float u = 1.f / (1.f + expf(-(gu + hu)));
        float n = tanhf(gn + r * hn);
        float hv = h[(size_t)b * HID + jc];
        h[(size_t)b * HID + jc] = (1.f - u) * n + u * hv;
    }
}

// ---------------------------------------------------------------- softmax / KL / sample
// thread g -> (b = g>>5, cat = g&31)
__global__ void k_soft(const float* __restrict__ priorL, const float* __restrict__ postL,
                       const float* __restrict__ gum_t, int* __restrict__ zidx,
                       float* __restrict__ kl_acc, int t) {
    int g = blockIdx.x * 256 + threadIdx.x;
    int b = g >> 5, cat = g & 31;
    const float* pl = priorL + (size_t)b * ZD + cat * NCLS;
    const float* ql = postL  + (size_t)b * ZD + cat * NCLS;
    const float* gm = gum_t  + (size_t)b * ZD + cat * NCLS;
    float mq = -1e30f, mp = -1e30f;
    for (int i = 0; i < NCLS; ++i) { mq = fmaxf(mq, ql[i]); mp = fmaxf(mp, pl[i]); }
    float sq = 0.f, sp = 0.f;
    for (int i = 0; i < NCLS; ++i) { sq += expf(ql[i] - mq); sp += expf(pl[i] - mp); }
    float lseq = mq + logf(sq), lsep = mp + logf(sp);
    float kl = 0.f; int best = 0; float bestv = ql[0] + gm[0];
    for (int i = 0; i < NCLS; ++i) {
        float lpq = ql[i] - lseq;
        float lpp = pl[i] - lsep;
        kl += expf(lpq) * (lpq - lpp);
        float s = ql[i] + gm[i];
        if (s > bestv) { bestv = s; best = i; }
    }
    zidx[b * 32 + cat] = best;
    __shared__ float red[256];
    red[threadIdx.x] = kl;
    __syncthreads();
    for (int s = 128; s > 0; s >>= 1) {
        if ((int)threadIdx.x < s) red[threadIdx.x] += red[threadIdx.x + s];
        __syncthreads();
    }
    if (threadIdx.x == 0) atomicAdd(&kl_acc[t], red[0]);
}

// ---------------------------------------------------------------- decoder/head layer 1
// dec1[b][m][col], m=0:d1(Wd1) 1:r1(Wr1) 2:c1(Wc1); latent = [h, z(one-hot)]
__global__ void k_dec1(const float* __restrict__ h, const int* __restrict__ zidx,
                       const float* __restrict__ Wd1, const float* __restrict__ bd1,
                       const float* __restrict__ Wr1, const float* __restrict__ br1,
                       const float* __restrict__ Wc1, const float* __restrict__ bc1,
                       float* __restrict__ dec1) {
    __shared__ float hs[4][1024];
    __shared__ int zs[4][32];
    int b0 = blockIdx.x * 4;
    int tid = threadIdx.x;
    for (int l = tid; l < 4 * 1024; l += 192)
        hs[l >> 10][l & 1023] = h[(size_t)b0 * HID + l];
    if (tid < 128) zs[tid >> 5][tid & 31] = zidx[b0 * 32 + tid];
    __syncthreads();
    int m = tid / 64;
    int col = tid & 63;
    const float* W    = (m == 0) ? Wd1 : ((m == 1) ? Wr1 : Wc1);
    const float* bias = (m == 0) ? bd1 : ((m == 1) ? br1 : bc1);
    for (int r = 0; r < 4; ++r) {
        float acc = bias[col];
        #pragma unroll 8
        for (int k = 0; k < HID; ++k) acc += hs[r][k] * W[k * 64 + col];
        #pragma unroll
        for (int c = 0; c < 32; ++c)
            acc += W[(size_t)(HID + c * 32 + zs[r][c]) * 64 + col];
        float v = acc > 0.f ? acc : (expf(acc) - 1.f);
        dec1[(size_t)(b0 + r) * 192 + m * 64 + col] = v;
    }
}

// ---------------------------------------------------------------- decoder layer 2 + losses
__global__ void k_dec2(const float* __restrict__ dec1,
                       const float* __restrict__ Wd2, const float* __restrict__ bd2,
                       const float* __restrict__ Wr2, const float* __restrict__ br2,
                       const float* __restrict__ Wc2, const float* __restrict__ bc2,
                       const int* __restrict__ obs_idx_t, const float* __restrict__ rew_t,
                       const float* __restrict__ done_t,
                       float* __restrict__ ce_acc, float* __restrict__ mse_acc,
                       float* __restrict__ bce_acc, int t) {
    int b = blockIdx.x, tid = threadIdx.x;
    __shared__ float d1[64], r1[64], c1[64];
    __shared__ float red[256];
    __shared__ float tlogit;
    if (tid < 192) {
        float v = dec1[(size_t)b * 192 + tid];
        if (tid < 64) d1[tid] = v;
        else if (tid < 128) r1[tid - 64] = v;
        else c1[tid - 128] = v;
    }
    __syncthreads();
    float lg[2];
    float mymax = -1e30f;
    #pragma unroll
    for (int jj = 0; jj < 2; ++jj) {
        int n = jj * 256 + tid;
        float acc = bd2[n];
        #pragma unroll 8
        for (int k = 0; k < 64; ++k) acc += d1[k] * Wd2[k * OBS + n];
        lg[jj] = acc;
        mymax = fmaxf(mymax, acc);
    }
    red[tid] = mymax; __syncthreads();
    for (int s = 128; s > 0; s >>= 1) {
        if (tid < s) red[tid] = fmaxf(red[tid], red[tid + s]);
        __syncthreads();
    }
    float M = red[0]; __syncthreads();
    red[tid] = expf(lg[0] - M) + expf(lg[1] - M); __syncthreads();
    for (int s = 128; s > 0; s >>= 1) {
        if (tid < s) red[tid] += red[tid + s];
        __syncthreads();
    }
    float lse = M + logf(red[0]);
    int tgt = obs_idx_t[b];
    if (tid == (tgt & 255)) tlogit = lg[tgt >> 8];
    __syncthreads();
    float ce_b = lse - tlogit;
    // reward head
    red[tid] = (tid < 64) ? r1[tid] * Wr2[tid] : 0.f; __syncthreads();
    for (int s = 128; s > 0; s >>= 1) {
        if (tid < s) red[tid] += red[tid + s];
        __syncthreads();
    }
    float r_pred = red[0] + br2[0]; __syncthreads();
    // continue head
    red[tid] = (tid < 64) ? c1[tid] * Wc2[tid] : 0.f; __syncthreads();
    for (int s = 128; s > 0; s >>= 1) {
        if (tid < s) red[tid] += red[tid + s];
        __syncthreads();
    }
    float c_pred = red[0] + bc2[0];
    if (tid == 0) {
        float rt = rew_t[b];
        float sgn = (rt > 0.f) ? 1.f : ((rt < 0.f) ? -1.f : 0.f);
        float r_tgt = sgn * log1pf(fabsf(rt));
        float diff = r_pred - r_tgt;
        float ct = 1.f - done_t[b];
        float bce = fmaxf(c_pred, 0.f) - c_pred * ct + log1pf(expf(-fabsf(c_pred)));
        atomicAdd(&ce_acc[t], ce_b);
        atomicAdd(&mse_acc[t], diff * diff);
        atomicAdd(&bce_acc[t], bce);
    }
}

// ---------------------------------------------------------------- final reduce
__global__ void k_final(const float* __restrict__ ce_acc, const float* __restrict__ mse_acc,
                        const float* __restrict__ bce_acc, const float* __restrict__ kl_acc,
                        float* __restrict__ out) {
    int t = threadIdx.x;   // 64 threads = 1 wave
    float ce = ce_acc[t] * (1.f / 256.f);
    float ms = mse_acc[t] * (1.f / 256.f);
    float bc = bce_acc[t] * (1.f / 256.f);
    float ka = kl_acc[t] * (1.f / 256.f);
    float kt = 0.8f * fmaxf(ka, 1.f) + 0.2f * fmaxf(ka, 1.f);
    for (int off = 32; off > 0; off >>= 1) {
        ce += __shfl_down(ce, off);
        ms += __shfl_down(ms, off);
        bc += __shfl_down(bc, off);
        kt += __shfl_down(kt, off);
    }
    if (t == 0) {
        ce *= (1.f / 64.f); ms *= (1.f / 64.f); bc *= (1.f / 64.f); kt *= (1.f / 64.f);
        out[0] = ce + ms + bc + kt;
        out[1] = ce; out[2] = ms; out[3] = bc; out[4] = kt;
    }
}

// ----------------------------------------------------------------------------------
extern "C" void kernel_launch(void* const* d_in, const int* in_sizes, int n_in,
                              void* d_out, int out_size, void* d_ws, size_t ws_size,
                              hipStream_t stream) {
    const float* obs  = (const float*)d_in[0];
    const float* act  = (const float*)d_in[1];
    const float* rew  = (const float*)d_in[2];
    const float* done = (const float*)d_in[3];
    const float* gum  = (const float*)d_in[4];
    const float* We1  = (const float*)d_in[5];
    const float* be1  = (const float*)d_in[6];
    const float* We2  = (const float*)d_in[7];
    const float* be2  = (const float*)d_in[8];
    const float* Wi   = (const float*)d_in[9];
    const float* Wh   = (const float*)d_in[10];
    const float* bi   = (const float*)d_in[11];
    const float* bh   = (const float*)d_in[12];
    const float* Wp1  = (const float*)d_in[13];
    const float* bp1  = (const float*)d_in[14];
    const float* Wp2  = (const float*)d_in[15];
    const float* bp2  = (const float*)d_in[16];
    const float* Wq1  = (const float*)d_in[17];
    const float* bq1  = (const float*)d_in[18];
    const float* Wq2  = (const float*)d_in[19];
    const float* bq2  = (const float*)d_in[20];
    const float* Wd1  = (const float*)d_in[21];
    const float* bd1  = (const float*)d_in[22];
    const float* Wd2  = (const float*)d_in[23];
    const float* bd2  = (const float*)d_in[24];
    const float* Wr1  = (const float*)d_in[25];
    const float* br1  = (const float*)d_in[26];
    const float* Wr2  = (const float*)d_in[27];
    const float* br2  = (const float*)d_in[28];
    const float* Wc1  = (const float*)d_in[29];
    const float* bc1  = (const float*)d_in[30];
    const float* Wc2  = (const float*)d_in[31];
    const float* bc2  = (const float*)d_in[32];

    float* ws    = (float*)d_ws;
    float* h      = ws + 0;         // 256*1024
    float* gh     = ws + 262144;    // 256*3072
    float* prior1 = ws + 1048576;   // 256*1024
    float* post1  = ws + 1310720;   // 256*1024
    float* priorL = ws + 1572864;   // 256*1024
    float* postL  = ws + 1835008;   // 256*1024
    float* dec1   = ws + 2097152;   // 256*192
    float* embed  = ws + 2146304;   // 16384*512
    float* acc    = ws + 10534912;  // ce[64] mse[64] bce[64] kl[64]
    int* obs_idx  = (int*)(ws + 10535168);  // 16384
    int* act_idx  = obs_idx + 16384;        // 16384
    int* zidx     = act_idx + 16384;        // 256*32

    hipMemsetAsync(h, 0, 262144 * sizeof(float), stream);
    hipMemsetAsync(acc, 0, 256 * sizeof(float), stream);

    k_idx<<<4096, 256, 0, stream>>>(obs, act, obs_idx, act_idx);
    k_embed<<<2048, 256, 0, stream>>>(obs_idx, We1, be1, We2, be2, embed);

    for (int t = 0; t < TT; ++t) {
        GemmJob jh = { h, HID, nullptr, 0, Wh, bh, gh, G3, 0 };
        k_gemm<<<dim3(48, 4, 1), 256, 0, stream>>>(jh, jh);
        k_gru_up<<<BB, 256, 0, stream>>>(gh, Wi, bi, act_idx + t * BB, zidx, h, t);
        GemmJob jp = { h, HID, nullptr, 0, Wp1, bp1, prior1, 1024, 1 };
        GemmJob jq = { h, HID, embed + (size_t)t * BB * EMB, EMB, Wq1, bq1, post1, 1024, 1 };
        k_gemm<<<dim3(16, 4, 2), 256, 0, stream>>>(jp, jq);
        GemmJob jP = { prior1, HID, nullptr, 0, Wp2, bp2, priorL, 1024, 0 };
        GemmJob jQ = { post1, HID, nullptr, 0, Wq2, bq2, postL, 1024, 0 };
        k_gemm<<<dim3(16, 4, 2), 256, 0, stream>>>(jP, jQ);
        k_soft<<<32, 256, 0, stream>>>(priorL, postL, gum + (size_t)t * BB * NCAT * NCLS,
                                       zidx, acc + 192, t);
        k_dec1<<<64, 192, 0, stream>>>(h, zidx, Wd1, bd1, Wr1, br1, Wc1, bc1, dec1);
        k_dec2<<<BB, 256, 0, stream>>>(dec1, Wd2, bd2, Wr2, br2, Wc2, bc2,
                                       obs_idx + t * BB, rew + t * BB, done + t * BB,
                                       acc + 0, acc + 64, acc + 128, t);
    }
    k_final<<<1, 64, 0, stream>>>(acc + 0, acc + 64, acc + 128, acc + 192, (float*)d_out);
}

// Round 2
// 5693.854 us; speedup vs baseline: 4.1859x; 4.1859x over previous
//
#include <hip/hip_runtime.h>
#include <math.h>

#define TT 64
#define BB 256
#define OBS 512
#define ACTN 16
#define EMB 512
#define HID 1024
#define NCAT 32
#define NCLS 32
#define ZD 1024
#define G3 3072

typedef short s16x8 __attribute__((ext_vector_type(8)));
typedef float floatx4 __attribute__((ext_vector_type(4)));

__device__ __forceinline__ unsigned short f2bf(float f) {
    unsigned int u = __float_as_uint(f);
    unsigned int r = (u + 0x7fffu + ((u >> 16) & 1u)) >> 16;
    return (unsigned short)r;
}
__device__ __forceinline__ float bf2f(unsigned short h) {
    return __uint_as_float(((unsigned int)h) << 16);
}

// ---------------------------------------------------------------- one-hot -> index
__global__ void k_idx(const float* __restrict__ obs, const float* __restrict__ act,
                      int* __restrict__ obs_idx, int* __restrict__ act_idx) {
    int wave = (blockIdx.x * blockDim.x + threadIdx.x) >> 6;
    int lane = threadIdx.x & 63;
    if (wave >= TT * BB) return;
    const float* o = obs + (size_t)wave * OBS;
    int found = -1;
    #pragma unroll
    for (int j = 0; j < 8; ++j) {
        float v = o[lane + 64 * j];
        if (v > 0.5f) found = lane + 64 * j;
    }
    unsigned long long m = __ballot(found >= 0);
    int src = __ffsll(m) - 1;
    int oidx = __shfl(found, src);
    int af = -1;
    if (lane < ACTN) {
        float v = act[(size_t)wave * ACTN + lane];
        if (v > 0.5f) af = lane;
    }
    unsigned long long m2 = __ballot(af >= 0);
    int src2 = __ffsll(m2) - 1;
    int aidx = __shfl(af, src2);
    if (lane == 0) { obs_idx[wave] = oidx; act_idx[wave] = aidx; }
}

// ---------------------------------------------------------------- transpose fp32 -> bf16 [C][ldo]
// out[(c)*ldo + ko + r] = in[r*C + c];  grid (C/32, R/32), block (32,8)
__global__ void k_transp(const float* __restrict__ in, int R, int C,
                         unsigned short* __restrict__ out, int ldo, int ko) {
    __shared__ float t[32][33];
    int c0 = blockIdx.x * 32, r0 = blockIdx.y * 32;
    int tx = threadIdx.x, ty = threadIdx.y;
    #pragma unroll
    for (int i = 0; i < 4; ++i)
        t[ty + 8 * i][tx] = in[(size_t)(r0 + ty + 8 * i) * C + c0 + tx];
    __syncthreads();
    #pragma unroll
    for (int i = 0; i < 4; ++i)
        out[(size_t)(c0 + ty + 8 * i) * ldo + ko + r0 + tx] = f2bf(t[tx][ty + 8 * i]);
}

// ---------------------------------------------------------------- pack dec/head biases
__global__ void k_pack_bias(const float* bd1, const float* br1, const float* bc1,
                            float* __restrict__ out) {
    int i = threadIdx.x;
    if (i < 64) out[i] = bd1[i];
    else if (i < 128) out[i] = br1[i - 64];
    else out[i] = bc1[i - 128];
}

// ---------------------------------------------------------------- e1 = elu(We1[oi] + be1) bf16
__global__ void k_e1(const int* __restrict__ obs_idx, const float* __restrict__ We1,
                     const float* __restrict__ be1, unsigned short* __restrict__ e1) {
    int g = blockIdx.x * 256 + threadIdx.x;
    int s = g >> 6, k = g & 63;
    float v = We1[obs_idx[s] * 64 + k] + be1[k];
    e1[g] = f2bf(v > 0.f ? v : (expf(v) - 1.f));
}

// ---------------------------------------------------------------- MFMA GEMM
// out[M,ldo] = act( X[M,K](ldx) @ WT[N,K]^T + bias + addb ), 64x64 tile / block (256 thr)
struct MJob {
    const unsigned short* X; int ldx;
    const unsigned short* WT;
    const float* bias;            // may be null
    const unsigned short* addb;   // optional bf16 add [M,N], used if flags&4
    void* out; int ldo;
    int N, K, flags;              // flags: 1=elu, 2=bf16 out, 4=addb
};

__global__ __launch_bounds__(256) void mfma_gemm(MJob j) {
    __shared__ unsigned short Xs[64][40];
    __shared__ unsigned short Ns[64][40];
    int tid = threadIdx.x;
    int m0 = blockIdx.y * 64, n0 = blockIdx.x * 64;
    int r = tid >> 2, p = (tid & 3) * 8;
    const unsigned short* xg = j.X + (size_t)(m0 + r) * j.ldx + p;
    const unsigned short* wg = j.WT + (size_t)(n0 + r) * j.K + p;
    int lane = tid & 63, wv = tid >> 6;
    int wm = (wv & 1) * 32, wn = (wv >> 1) * 32;
    int mi = lane & 15, q = lane >> 4;
    floatx4 acc00 = {0.f, 0.f, 0.f, 0.f};
    floatx4 acc01 = acc00, acc10 = acc00, acc11 = acc00;
    for (int kt = 0; kt < j.K; kt += 32) {
        *(float4*)&Xs[r][p] = *(const float4*)(xg + kt);
        *(float4*)&Ns[r][p] = *(const float4*)(wg + kt);
        __syncthreads();
        s16x8 a0 = *(const s16x8*)&Xs[wm + mi][q * 8];
        s16x8 a1 = *(const s16x8*)&Xs[wm + 16 + mi][q * 8];
        s16x8 b0 = *(const s16x8*)&Ns[wn + mi][q * 8];
        s16x8 b1 = *(const s16x8*)&Ns[wn + 16 + mi][q * 8];
        acc00 = __builtin_amdgcn_mfma_f32_16x16x32_bf16(a0, b0, acc00, 0, 0, 0);
        acc01 = __builtin_amdgcn_mfma_f32_16x16x32_bf16(a0, b1, acc01, 0, 0, 0);
        acc10 = __builtin_amdgcn_mfma_f32_16x16x32_bf16(a1, b0, acc10, 0, 0, 0);
        acc11 = __builtin_amdgcn_mfma_f32_16x16x32_bf16(a1, b1, acc11, 0, 0, 0);
        __syncthreads();
    }
    #pragma unroll
    for (int i = 0; i < 2; ++i) {
        #pragma unroll
        for (int jj = 0; jj < 2; ++jj) {
            floatx4 a = (i == 0) ? ((jj == 0) ? acc00 : acc01)
                                 : ((jj == 0) ? acc10 : acc11);
            int col = n0 + wn + jj * 16 + mi;
            float badd = j.bias ? j.bias[col] : 0.f;
            #pragma unroll
            for (int rg = 0; rg < 4; ++rg) {
                int row = m0 + wm + i * 16 + q * 4 + rg;
                float v = a[rg] + badd;
                if (j.flags & 4) v += bf2f(j.addb[(size_t)row * j.N + col]);
                if (j.flags & 1) v = v > 0.f ? v : (expf(v) - 1.f);
                if (j.flags & 2)
                    ((unsigned short*)j.out)[(size_t)row * j.ldo + col] = f2bf(v);
                else
                    ((float*)j.out)[(size_t)row * j.ldo + col] = v;
            }
        }
    }
}

// ---------------------------------------------------------------- GRU elementwise
// gh = h@Wh, giz = z@Wi_z (both fp32 [256,3072]); act row + biases added here
__global__ void k_gru(const float* __restrict__ gh, const float* __restrict__ giz,
                      const float* __restrict__ Wi, const float* __restrict__ bi,
                      const float* __restrict__ bh, const int* __restrict__ act_t,
                      float* __restrict__ h_state, unsigned short* __restrict__ xz_t) {
    int b = blockIdx.x;
    int arow = ZD + act_t[b];
    const float* wa = Wi + (size_t)arow * G3;
    #pragma unroll
    for (int it = 0; it < 4; ++it) {
        int jc = it * 256 + threadIdx.x;
        size_t o = (size_t)b * G3 + jc;
        float gir = giz[o]        + wa[jc]        + bi[jc];
        float giu = giz[o + 1024] + wa[1024 + jc] + bi[1024 + jc];
        float gin = giz[o + 2048] + wa[2048 + jc] + bi[2048 + jc];
        float ghr = gh[o]        + bh[jc];
        float ghu = gh[o + 1024] + bh[1024 + jc];
        float ghn = gh[o + 2048] + bh[2048 + jc];
        float rr = 1.f / (1.f + expf(-(gir + ghr)));
        float uu = 1.f / (1.f + expf(-(giu + ghu)));
        float nn = tanhf(gin + rr * ghn);
        float hv = h_state[(size_t)b * HID + jc];
        float hn2 = (1.f - uu) * nn + uu * hv;
        h_state[(size_t)b * HID + jc] = hn2;
        xz_t[(size_t)b * 2048 + jc] = f2bf(hn2);
    }
}

// ---------------------------------------------------------------- gumbel-argmax sample -> z one-hot
__global__ void k_sample(const unsigned short* __restrict__ postL_t,
                         const float* __restrict__ gum_t,
                         unsigned short* __restrict__ xz_t) {
    int g = blockIdx.x * 256 + threadIdx.x;    // 8192 = 256 b * 32 cat
    int b = g >> 5, cat = g & 31;
    const unsigned short* ql = postL_t + (size_t)b * ZD + cat * NCLS;
    const float* gm = gum_t + (size_t)b * ZD + cat * NCLS;
    int best = 0; float bv = -1e30f;
    #pragma unroll
    for (int i = 0; i < NCLS; ++i) {
        float s = bf2f(ql[i]) + gm[i];
        if (s > bv) { bv = s; best = i; }
    }
    unsigned short* zo = xz_t + (size_t)b * 2048 + 1024 + cat * NCLS;
    #pragma unroll
    for (int i = 0; i < NCLS; ++i) zo[i] = (i == best) ? 0x3F80 : 0;
}

// ---------------------------------------------------------------- KL (deferred, all t)
__global__ void k_kl(const unsigned short* __restrict__ postL,
                     const unsigned short* __restrict__ priorL,
                     float* __restrict__ kl_acc) {
    int g = blockIdx.x * 256 + threadIdx.x;    // 16384*32
    int sidx = g >> 5, cat = g & 31;
    const unsigned short* ql = postL + (size_t)sidx * ZD + cat * NCLS;
    const unsigned short* pl = priorL + (size_t)sidx * ZD + cat * NCLS;
    float vq[32], vp[32];
    float mq = -1e30f, mp = -1e30f;
    #pragma unroll
    for (int i = 0; i < NCLS; ++i) {
        vq[i] = bf2f(ql[i]); vp[i] = bf2f(pl[i]);
        mq = fmaxf(mq, vq[i]); mp = fmaxf(mp, vp[i]);
    }
    float sq = 0.f, sp = 0.f;
    #pragma unroll
    for (int i = 0; i < NCLS; ++i) { sq += expf(vq[i] - mq); sp += expf(vp[i] - mp); }
    float lseq = mq + logf(sq), lsep = mp + logf(sp);
    float kl = 0.f;
    #pragma unroll
    for (int i = 0; i < NCLS; ++i) {
        float lpq = vq[i] - lseq;
        kl += expf(lpq) * (lpq - (vp[i] - lsep));
    }
    __shared__ float red[256];
    red[threadIdx.x] = kl;
    __syncthreads();
    for (int s = 128; s > 0; s >>= 1) {
        if ((int)threadIdx.x < s) red[threadIdx.x] += red[threadIdx.x + s];
        __syncthreads();
    }
    if (threadIdx.x == 0) atomicAdd(&kl_acc[sidx >> 8], red[0]);
}

// ---------------------------------------------------------------- CE over 512 logits (wave/sample)
__global__ void k_ce(const unsigned short* __restrict__ logits,
                     const int* __restrict__ obs_idx, float* __restrict__ ce_acc) {
    int s = (blockIdx.x * 256 + threadIdx.x) >> 6;
    int lane = threadIdx.x & 63;
    union { float4 f4; unsigned short u[8]; } raw;
    raw.f4 = *(const float4*)(logits + (size_t)s * OBS + lane * 8);
    float v[8];
    float m = -1e30f;
    #pragma unroll
    for (int i = 0; i < 8; ++i) { v[i] = bf2f(raw.u[i]); m = fmaxf(m, v[i]); }
    #pragma unroll
    for (int off = 32; off > 0; off >>= 1) m = fmaxf(m, __shfl_xor(m, off));
    float sum = 0.f;
    #pragma unroll
    for (int i = 0; i < 8; ++i) sum += expf(v[i] - m);
    #pragma unroll
    for (int off = 32; off > 0; off >>= 1) sum += __shfl_xor(sum, off);
    float lse = m + logf(sum);
    int tgt = obs_idx[s];
    float tv = 0.f;
    #pragma unroll
    for (int i = 0; i < 8; ++i) if (lane * 8 + i == tgt) tv = v[i];
    #pragma unroll
    for (int off = 32; off > 0; off >>= 1) tv += __shfl_xor(tv, off);
    if (lane == 0) atomicAdd(&ce_acc[s >> 8], lse - tv);
}

// ---------------------------------------------------------------- reward / continue heads
__global__ void k_heads(const unsigned short* __restrict__ dec1,
                        const float* __restrict__ Wr2, const float* __restrict__ br2,
                        const float* __restrict__ Wc2, const float* __restrict__ bc2,
                        const float* __restrict__ rew, const float* __restrict__ done,
                        float* __restrict__ mse_acc, float* __restrict__ bce_acc) {
    int s = (blockIdx.x * 256 + threadIdx.x) >> 6;
    int lane = threadIdx.x & 63;
    float vr = bf2f(dec1[(size_t)s * 192 + 64 + lane]) * Wr2[lane];
    float vc = bf2f(dec1[(size_t)s * 192 + 128 + lane]) * Wc2[lane];
    #pragma unroll
    for (int off = 32; off > 0; off >>= 1) {
        vr += __shfl_xor(vr, off);
        vc += __shfl_xor(vc, off);
    }
    if (lane == 0) {
        float r_pred = vr + br2[0], c_pred = vc + bc2[0];
        float rt = rew[s];
        float sgn = (rt > 0.f) ? 1.f : ((rt < 0.f) ? -1.f : 0.f);
        float r_tgt = sgn * log1pf(fabsf(rt));
        float d = r_pred - r_tgt;
        float ct = 1.f - done[s];
        float bce = fmaxf(c_pred, 0.f) - c_pred * ct + log1pf(expf(-fabsf(c_pred)));
        atomicAdd(&mse_acc[s >> 8], d * d);
        atomicAdd(&bce_acc[s >> 8], bce);
    }
}

// ---------------------------------------------------------------- final reduce
__global__ void k_final(const float* __restrict__ ce_acc, const float* __restrict__ mse_acc,
                        const float* __restrict__ bce_acc, const float* __restrict__ kl_acc,
                        float* __restrict__ out) {
    int t = threadIdx.x;
    float ce = ce_acc[t] * (1.f / 256.f);
    float ms = mse_acc[t] * (1.f / 256.f);
    float bc = bce_acc[t] * (1.f / 256.f);
    float ka = kl_acc[t] * (1.f / 256.f);
    float kt = fmaxf(ka, 1.f);
    #pragma unroll
    for (int off = 32; off > 0; off >>= 1) {
        ce += __shfl_down(ce, off);
        ms += __shfl_down(ms, off);
        bc += __shfl_down(bc, off);
        kt += __shfl_down(kt, off);
    }
    if (t == 0) {
        ce *= (1.f / 64.f); ms *= (1.f / 64.f); bc *= (1.f / 64.f); kt *= (1.f / 64.f);
        out[0] = ce + ms + bc + kt;
        out[1] = ce; out[2] = ms; out[3] = bc; out[4] = kt;
    }
}

// ----------------------------------------------------------------------------------
extern "C" void kernel_launch(void* const* d_in, const int* in_sizes, int n_in,
                              void* d_out, int out_size, void* d_ws, size_t ws_size,
                              hipStream_t stream) {
    const float* obs  = (const float*)d_in[0];
    const float* act  = (const float*)d_in[1];
    const float* rew  = (const float*)d_in[2];
    const float* done = (const float*)d_in[3];
    const float* gum  = (const float*)d_in[4];
    const float* We1  = (const float*)d_in[5];
    const float* be1  = (const float*)d_in[6];
    const float* We2  = (const float*)d_in[7];
    const float* be2  = (const float*)d_in[8];
    const float* Wi   = (const float*)d_in[9];
    const float* Wh   = (const float*)d_in[10];
    const float* bi   = (const float*)d_in[11];
    const float* bh   = (const float*)d_in[12];
    const float* Wp1  = (const float*)d_in[13];
    const float* bp1  = (const float*)d_in[14];
    const float* Wp2  = (const float*)d_in[15];
    const float* bp2  = (const float*)d_in[16];
    const float* Wq1  = (const float*)d_in[17];
    const float* bq1  = (const float*)d_in[18];
    const float* Wq2  = (const float*)d_in[19];
    const float* bq2  = (const float*)d_in[20];
    const float* Wd1  = (const float*)d_in[21];
    const float* bd1  = (const float*)d_in[22];
    const float* Wd2  = (const float*)d_in[23];
    const float* bd2  = (const float*)d_in[24];
    const float* Wr1  = (const float*)d_in[25];
    const float* br1  = (const float*)d_in[26];
    const float* Wr2  = (const float*)d_in[27];
    const float* br2  = (const float*)d_in[28];
    const float* Wc1  = (const float*)d_in[29];
    const float* bc1  = (const float*)d_in[30];
    const float* Wc2  = (const float*)d_in[31];
    const float* bc2  = (const float*)d_in[32];

    char* base = (char*)d_ws;
    size_t off = 0;
    auto alloc = [&](size_t bytes) -> char* {
        char* p = base + off;
        off += (bytes + 255) & ~(size_t)255;
        return p;
    };
    unsigned short* WhT   = (unsigned short*)alloc(3072u * 1024 * 2);
    unsigned short* WizT  = (unsigned short*)alloc(3072u * 1024 * 2);
    unsigned short* Wq1aT = (unsigned short*)alloc(1024u * 1024 * 2);
    unsigned short* Wq1bT = (unsigned short*)alloc(1024u * 512 * 2);
    unsigned short* Wq2T  = (unsigned short*)alloc(1024u * 1024 * 2);
    unsigned short* Wp1T  = (unsigned short*)alloc(1024u * 1024 * 2);
    unsigned short* Wp2T  = (unsigned short*)alloc(1024u * 1024 * 2);
    unsigned short* WdrcT = (unsigned short*)alloc(192u * 2048 * 2);
    unsigned short* Wd2T  = (unsigned short*)alloc(512u * 64 * 2);
    unsigned short* We2T  = (unsigned short*)alloc(512u * 64 * 2);
    float*          b_drc = (float*)alloc(192 * 4);
    unsigned short* XZ    = (unsigned short*)alloc(65u * 256 * 2048 * 2);   // 68 MB
    float*          h_st  = (float*)alloc(256u * 1024 * 4);
    float*          gh    = (float*)alloc(256u * 3072 * 4);
    float*          giz   = (float*)alloc(256u * 3072 * 4);
    unsigned short* post1 = (unsigned short*)alloc(256u * 1024 * 2);
    unsigned short* postL = (unsigned short*)alloc(16384u * 1024 * 2);      // 32 MB (also logits later)
    unsigned short* Eq    = (unsigned short*)alloc(16384u * 1024 * 2);      // 32 MB (also priorL later)
    unsigned short* pri1  = (unsigned short*)alloc(16384u * 1024 * 2);      // 32 MB
    unsigned short* dec1  = (unsigned short*)alloc(16384u * 192 * 2);
    float*          acc   = (float*)alloc(256 * 4);
    int*            obs_idx = (int*)alloc(16384 * 4);
    int*            act_idx = (int*)alloc(16384 * 4);
    // aliases into pri1 region (only used in setup, before pri1 is written)
    unsigned short* embed = pri1;                                           // 16 MB
    unsigned short* e1    = pri1 + 16384u * 512;                            // 2 MB

    hipMemsetAsync(XZ, 0, 256u * 2048 * 2, stream);       // slot 0 = [h0|z0] = 0
    hipMemsetAsync(h_st, 0, 256u * 1024 * 4, stream);
    hipMemsetAsync(acc, 0, 256 * 4, stream);

    k_idx<<<4096, 256, 0, stream>>>(obs, act, obs_idx, act_idx);

    dim3 tb(32, 8);
    k_transp<<<dim3(96, 32), tb, 0, stream>>>(Wh,  1024, 3072, WhT, 1024, 0);
    k_transp<<<dim3(96, 32), tb, 0, stream>>>(Wi,  1024, 3072, WizT, 1024, 0);
    k_transp<<<dim3(32, 32), tb, 0, stream>>>(Wq1, 1024, 1024, Wq1aT, 1024, 0);
    k_transp<<<dim3(32, 16), tb, 0, stream>>>(Wq1 + 1024u * 1024, 512, 1024, Wq1bT, 512, 0);
    k_transp<<<dim3(32, 32), tb, 0, stream>>>(Wq2, 1024, 1024, Wq2T, 1024, 0);
    k_transp<<<dim3(32, 32), tb, 0, stream>>>(Wp1, 1024, 1024, Wp1T, 1024, 0);
    k_transp<<<dim3(32, 32), tb, 0, stream>>>(Wp2, 1024, 1024, Wp2T, 1024, 0);
    k_transp<<<dim3(2, 64),  tb, 0, stream>>>(Wd1, 2048, 64, WdrcT, 2048, 0);
    k_transp<<<dim3(2, 64),  tb, 0, stream>>>(Wr1, 2048, 64, WdrcT + 64u * 2048, 2048, 0);
    k_transp<<<dim3(2, 64),  tb, 0, stream>>>(Wc1, 2048, 64, WdrcT + 128u * 2048, 2048, 0);
    k_transp<<<dim3(16, 2),  tb, 0, stream>>>(Wd2, 64, 512, Wd2T, 64, 0);
    k_transp<<<dim3(16, 2),  tb, 0, stream>>>(We2, 64, 512, We2T, 64, 0);
    k_pack_bias<<<1, 192, 0, stream>>>(bd1, br1, bc1, b_drc);

    // ---- embed & Eq precompute (all 64 steps at once)
    k_e1<<<4096, 256, 0, stream>>>(obs_idx, We1, be1, e1);
    {   // embed = e1 @ We2 + be2   [16384,64]@[64,512] -> bf16
        MJob m = { e1, 64, We2T, be2, nullptr, embed, 512, 512, 64, 2 };
        mfma_gemm<<<dim3(8, 256), 256, 0, stream>>>(m);
    }
    {   // Eq = embed @ Wq1b + bq1  [16384,512]@[512,1024] -> bf16
        MJob m = { embed, 512, Wq1bT, bq1, nullptr, Eq, 1024, 1024, 512, 2 };
        mfma_gemm<<<dim3(16, 256), 256, 0, stream>>>(m);
    }

    // ---- serial scan
    for (int t = 1; t <= TT; ++t) {
        unsigned short* xz_prev = XZ + (size_t)(t - 1) * 256 * 2048;
        unsigned short* xz_cur  = XZ + (size_t)t * 256 * 2048;
        {   // gh = h_{t-1} @ Wh
            MJob m = { xz_prev, 2048, WhT, nullptr, nullptr, gh, 3072, 3072, 1024, 0 };
            mfma_gemm<<<dim3(48, 4), 256, 0, stream>>>(m);
        }
        {   // giz = z_{t-1} @ Wi[0:1024]
            MJob m = { xz_prev + 1024, 2048, WizT, nullptr, nullptr, giz, 3072, 3072, 1024, 0 };
            mfma_gemm<<<dim3(48, 4), 256, 0, stream>>>(m);
        }
        k_gru<<<256, 256, 0, stream>>>(gh, giz, Wi, bi, bh, act_idx + (t - 1) * 256,
                                       h_st, xz_cur);
        {   // post1 = elu(h_t @ Wq1a + Eq_t)
            MJob m = { xz_cur, 2048, Wq1aT, nullptr, Eq + (size_t)(t - 1) * 262144,
                       post1, 1024, 1024, 1024, 1 | 2 | 4 };
            mfma_gemm<<<dim3(16, 4), 256, 0, stream>>>(m);
        }
        {   // postL_t = post1 @ Wq2 + bq2
            MJob m = { post1, 1024, Wq2T, bq2, nullptr,
                       postL + (size_t)(t - 1) * 262144, 1024, 1024, 1024, 2 };
            mfma_gemm<<<dim3(16, 4), 256, 0, stream>>>(m);
        }
        k_sample<<<32, 256, 0, stream>>>(postL + (size_t)(t - 1) * 262144,
                                         gum + (size_t)(t - 1) * 262144, xz_cur);
    }

    // ---- deferred batched passes over all 16384 (t,b)
    unsigned short* Hall = XZ + (size_t)256 * 2048;   // slots 1..64, h at col 0, ldx 2048
    {   // prior1 = elu(H @ Wp1 + bp1)
        MJob m = { Hall, 2048, Wp1T, bp1, nullptr, pri1, 1024, 1024, 1024, 1 | 2 };
        mfma_gemm<<<dim3(16, 256), 256, 0, stream>>>(m);
    }
    {   // priorL = prior1 @ Wp2 + bp2  (reuse Eq buffer)
        MJob m = { pri1, 1024, Wp2T, bp2, nullptr, Eq, 1024, 1024, 1024, 2 };
        mfma_gemm<<<dim3(16, 256), 256, 0, stream>>>(m);
    }
    k_kl<<<2048, 256, 0, stream>>>(postL, Eq, acc + 192);
    {   // dec1 = elu([h|z] @ [Wd1|Wr1|Wc1] + b)   [16384,2048]@[2048,192]
        MJob m = { Hall, 2048, WdrcT, b_drc, nullptr, dec1, 192, 192, 2048, 1 | 2 };
        mfma_gemm<<<dim3(3, 256), 256, 0, stream>>>(m);
    }
    {   // logits = dec1[:, :64] @ Wd2 + bd2  (reuse postL buffer)
        MJob m = { dec1, 192, Wd2T, bd2, nullptr, postL, 512, 512, 64, 2 };
        mfma_gemm<<<dim3(8, 256), 256, 0, stream>>>(m);
    }
    k_ce<<<4096, 256, 0, stream>>>(postL, obs_idx, acc + 0);
    k_heads<<<4096, 256, 0, stream>>>(dec1, Wr2, br2, Wc2, bc2, rew, done,
                                      acc + 64, acc + 128);
    k_final<<<1, 64, 0, stream>>>(acc + 0, acc + 64, acc + 128, acc + 192, (float*)d_out);
}